// Round 21
// baseline (1361.206 us; speedup 1.0000x reference)
//
#include <hip/hip_runtime.h>
#include <hip/hip_bf16.h>
#include <cstddef>

// Problem constants: BS=4, SEQ=2048, EMB=512, BD=8, H=64; tokens M=8192.

typedef _Float16 f16;
typedef _Float16 f16x4 __attribute__((ext_vector_type(4)));
typedef _Float16 f16x8 __attribute__((ext_vector_type(8)));
typedef float f32x4 __attribute__((ext_vector_type(4)));

// ---------------------------------------------------------------------------
// One-shot fp32 -> (hi,lo) f16 plane split.  v = hi + lo.
// ---------------------------------------------------------------------------
__global__ __launch_bounds__(256)
void split_kernel(const float* __restrict__ in, f16* __restrict__ hi,
                  f16* __restrict__ lo, int n) {
  const int idx = (blockIdx.x * 256 + threadIdx.x) * 4;
  if (idx >= n) return;
  float4 v = *(const float4*)(in + idx);
  f16x4 h, l;
  h.x = (f16)v.x; l.x = (f16)(v.x - (float)h.x);
  h.y = (f16)v.y; l.y = (f16)(v.y - (float)h.y);
  h.z = (f16)v.z; l.z = (f16)(v.z - (float)h.z);
  h.w = (f16)v.w; l.w = (f16)(v.w - (float)h.w);
  *(f16x4*)(hi + idx) = h;
  *(f16x4*)(lo + idx) = l;
}

// ---------------------------------------------------------------------------
// NEW: 128x128-tile SINGLE-buffered DMA GEMM, 4 blocks/CU (24KB LDS,
// VGPR ~88, grid 1024 at M=4096).  Trades in-block prefetch for 4-deep
// inter-block TLP: one block's stage/drain phase is covered by the other
// three blocks' MFMA phases (m114 co-scheduling).  Untested quadrant:
// R9 = dbuf 2blk (780us-eq), R15 = 256^2 dbuf 1blk (704us), R19 void
// (grid==CUs).  Body = proven gemm_dma2 minus dbuf; EPI=1 epilogue =
// proven R6 gemm2_dma norm fusion at this exact 64x64-wave geometry.
// 1-D grid, XCD swizzle + n-major decode (lg_mb m-tiles per B panel).
// EPI 0: relu -> hi/lo plane out (Ohi, Olo = Ohi + M*N)
// EPI 1: fused block-norm -> BLKT scan layout [b_local,h,s,64] fp32
// ---------------------------------------------------------------------------
template<int EPI>
__global__ __launch_bounds__(256, 2)
void gemm_sb(const f16* __restrict__ Ahi, const f16* __restrict__ Alo,
             const f16* __restrict__ Bhi, const f16* __restrict__ Blo,
             const float* __restrict__ bias, void* __restrict__ Ov,
             int M, int N, int K, int roff, int lg_mb) {
  __shared__ f16 S[4][128 * 32];
  const int tid = threadIdx.x, lane = tid & 63, wid = tid >> 6;
  const int total = gridDim.x, chunk = total >> 3;
  const int swz = (blockIdx.x & 7) * chunk + (blockIdx.x >> 3);
  const int mtile = swz & ((1 << lg_mb) - 1);
  const int ntile = swz >> lg_mb;
  const int m0 = mtile << 7, n0 = ntile << 7;
  const int wr = wid >> 1, wc = wid & 1;
  const int fr = lane & 15, g = lane >> 4;
  const int r_sub = lane >> 2, lc = lane & 3;

  f32x4 acc[4][4];
#pragma unroll
  for (int m = 0; m < 4; ++m)
#pragma unroll
    for (int n = 0; n < 4; ++n) acc[m][n] = (f32x4)0.f;

  const f16* gsrc = (wid == 0) ? Ahi + (size_t)m0 * K
                  : (wid == 1) ? Alo + (size_t)m0 * K
                  : (wid == 2) ? Bhi + (size_t)n0 * K
                               : Blo + (size_t)n0 * K;

  auto stage = [&](int k0) {                        // 8 gload_lds per wave
    f16* ld = &S[wid][0];
#pragma unroll
    for (int i = 0; i < 8; ++i) {
      const int r = i * 16 + r_sub;                 // plane row 0..127
      const int sg = (lc - r - (r >> 2)) & 3;       // source chunk for slot lc
      const f16* sp = gsrc + (size_t)r * K + k0 + sg * 8;
      __builtin_amdgcn_global_load_lds(
          (const __attribute__((address_space(1))) unsigned int*)sp,
          (__attribute__((address_space(3))) unsigned int*)(ld + i * 512),
          16, 0, 0);
    }
  };

  const int NT = K >> 5;
  for (int t = 0; t < NT; ++t) {
    stage(t << 5);
    __syncthreads();  // drain DMA (compiler vmcnt) + all waves staged

    f16x8 ah[4], al[4], bh[4], bl[4];
#pragma unroll
    for (int m = 0; m < 4; ++m) {
      const int rr = wr * 64 + m * 16 + fr;
      const int off = rr * 32 + (((g + rr + (rr >> 2)) & 3) << 3);
      ah[m] = *(const f16x8*)&S[0][off];
      al[m] = *(const f16x8*)&S[1][off];
    }
#pragma unroll
    for (int n = 0; n < 4; ++n) {
      const int rr = wc * 64 + n * 16 + fr;
      const int off = rr * 32 + (((g + rr + (rr >> 2)) & 3) << 3);
      bh[n] = *(const f16x8*)&S[2][off];
      bl[n] = *(const f16x8*)&S[3][off];
    }
    // 3 passes of 16 independent MFMAs; per-acc order hh,hl,lh preserved.
#pragma unroll
    for (int m = 0; m < 4; ++m)
#pragma unroll
      for (int n = 0; n < 4; ++n)
        acc[m][n] = __builtin_amdgcn_mfma_f32_16x16x32_f16(ah[m], bh[n], acc[m][n], 0, 0, 0);
#pragma unroll
    for (int m = 0; m < 4; ++m)
#pragma unroll
      for (int n = 0; n < 4; ++n)
        acc[m][n] = __builtin_amdgcn_mfma_f32_16x16x32_f16(ah[m], bl[n], acc[m][n], 0, 0, 0);
#pragma unroll
    for (int m = 0; m < 4; ++m)
#pragma unroll
      for (int n = 0; n < 4; ++n)
        acc[m][n] = __builtin_amdgcn_mfma_f32_16x16x32_f16(al[m], bh[n], acc[m][n], 0, 0, 0);

    __syncthreads();  // all reads done before next tile's stage overwrites
  }

  // Epilogue.  frag (m,n): col = n0+wc*64+n*16+fr, row = m0+wr*64+m*16+fq*4+r
  const int fq = lane >> 4;
  float bz[4];
#pragma unroll
  for (int n = 0; n < 4; ++n) bz[n] = bias[n0 + wc * 64 + n * 16 + fr];

  if (EPI == 0) {
    f16* Ohi = (f16*)Ov;
    f16* Olo = Ohi + (size_t)M * N;
#pragma unroll
    for (int m = 0; m < 4; ++m)
#pragma unroll
      for (int n = 0; n < 4; ++n) {
        const int col = n0 + wc * 64 + n * 16 + fr;
#pragma unroll
        for (int r = 0; r < 4; ++r) {
          const int row = m0 + wr * 64 + m * 16 + fq * 4 + r;
          float v = fmaxf(acc[m][n][r] + bz[n], 0.f);
          f16 h = (f16)v;
          f16 l = (f16)(v - (float)h);
          Ohi[(size_t)row * N + col] = h;
          Olo[(size_t)row * N + col] = l;
        }
      }
  } else {
    // fused block-norm (R6-proven at this geometry): wave col span = 1 head.
    // i = 2n + (fr>>3), j = fr&7; mean/norm via shfl_xor(8); max-j via 1,2,4.
    float* O = (float*)Ov;
#pragma unroll
    for (int m = 0; m < 4; ++m) {
#pragma unroll
      for (int r = 0; r < 4; ++r) {
        float v[4];
#pragma unroll
        for (int n = 0; n < 4; ++n) v[n] = acc[m][n][r] + bz[n];
        float s = v[0] + v[1] + v[2] + v[3];
        s += __shfl_xor(s, 8);
        const float mean = s * 0.125f;
        float t = 0.f;
#pragma unroll
        for (int n = 0; n < 4; ++n) {
          v[n] -= mean;
          t += exp2f(1.2f * log2f(fabsf(v[n])));  // |x|^1.2 (0 -> 0)
        }
        t += __shfl_xor(t, 8);                    // sum over i
        float nrm = exp2f((1.0f / 1.2f) * log2f(t));
        nrm = fmaxf(nrm, __shfl_xor(nrm, 1));
        nrm = fmaxf(nrm, __shfl_xor(nrm, 2));
        nrm = fmaxf(nrm, __shfl_xor(nrm, 4));     // max over j
        const float inv = 1.f / nrm;
        const int row = m0 + wr * 64 + m * 16 + fq * 4 + r;
        const int grow = roff + row;
        const int bb = grow >> 11, ss = grow & 2047;  // local batch (M=4096)
#pragma unroll
        for (int n = 0; n < 4; ++n) {
          const int col = n0 + wc * 64 + n * 16 + fr;
          O[(((size_t)(bb * 64 + (col >> 6)) * 2048 + ss) << 6) + (col & 63)] = v[n] * inv;
        }
      }
    }
  }
}

// ---------------------------------------------------------------------------
// 128x128 double-buffered DMA GEMM (V-path only), unchanged from R20.
// EPI 0: relu -> hi/lo planes; EPI 2: plain -> VT [b,h,s,8].
// ---------------------------------------------------------------------------
template<int EPI>
__global__ __launch_bounds__(256, 2)
void gemm_dma2(const f16* __restrict__ Ahi, const f16* __restrict__ Alo,
               const f16* __restrict__ Bhi, const f16* __restrict__ Blo,
               const float* __restrict__ bias, void* __restrict__ Ov,
               int M, int N, int K, int roff, int lg_mb) {
  __shared__ f16 S[2][4][128 * 32];
  const int tid = threadIdx.x, lane = tid & 63, wid = tid >> 6;
  const int total = gridDim.x, chunk = total >> 3;
  const int swz = (blockIdx.x & 7) * chunk + (blockIdx.x >> 3);
  const int mtile = swz & ((1 << lg_mb) - 1);
  const int ntile = swz >> lg_mb;
  const int m0 = mtile << 7, n0 = ntile << 7;
  const int wr = wid >> 1, wc = wid & 1;
  const int fr = lane & 15, g = lane >> 4;
  const int r_sub = lane >> 2, lc = lane & 3;

  f32x4 acc[4][4];
#pragma unroll
  for (int m = 0; m < 4; ++m)
#pragma unroll
    for (int n = 0; n < 4; ++n) acc[m][n] = (f32x4)0.f;

  const f16* gsrc = (wid == 0) ? Ahi + (size_t)m0 * K
                  : (wid == 1) ? Alo + (size_t)m0 * K
                  : (wid == 2) ? Bhi + (size_t)n0 * K
                               : Blo + (size_t)n0 * K;

  auto stage = [&](int b, int k0) {
    f16* ld = &S[b][wid][0];
#pragma unroll
    for (int i = 0; i < 8; ++i) {
      const int r = i * 16 + r_sub;
      const int sg = (lc - r - (r >> 2)) & 3;
      const f16* sp = gsrc + (size_t)r * K + k0 + sg * 8;
      __builtin_amdgcn_global_load_lds(
          (const __attribute__((address_space(1))) unsigned int*)sp,
          (__attribute__((address_space(3))) unsigned int*)(ld + i * 512),
          16, 0, 0);
    }
  };

  const int NT = K >> 5;
  stage(0, 0);
  __syncthreads();
  int cur = 0;
  for (int t = 0; t < NT; ++t) {
    if (t + 1 < NT) stage(cur ^ 1, (t + 1) << 5);
    f16x8 ah[4], al[4], bh[4], bl[4];
#pragma unroll
    for (int m = 0; m < 4; ++m) {
      const int rr = wr * 64 + m * 16 + fr;
      const int off = rr * 32 + (((g + rr + (rr >> 2)) & 3) << 3);
      ah[m] = *(const f16x8*)&S[cur][0][off];
      al[m] = *(const f16x8*)&S[cur][1][off];
    }
#pragma unroll
    for (int n = 0; n < 4; ++n) {
      const int rr = wc * 64 + n * 16 + fr;
      const int off = rr * 32 + (((g + rr + (rr >> 2)) & 3) << 3);
      bh[n] = *(const f16x8*)&S[cur][2][off];
      bl[n] = *(const f16x8*)&S[cur][3][off];
    }
#pragma unroll
    for (int m = 0; m < 4; ++m)
#pragma unroll
      for (int n = 0; n < 4; ++n)
        acc[m][n] = __builtin_amdgcn_mfma_f32_16x16x32_f16(ah[m], bh[n], acc[m][n], 0, 0, 0);
#pragma unroll
    for (int m = 0; m < 4; ++m)
#pragma unroll
      for (int n = 0; n < 4; ++n)
        acc[m][n] = __builtin_amdgcn_mfma_f32_16x16x32_f16(ah[m], bl[n], acc[m][n], 0, 0, 0);
#pragma unroll
    for (int m = 0; m < 4; ++m)
#pragma unroll
      for (int n = 0; n < 4; ++n)
        acc[m][n] = __builtin_amdgcn_mfma_f32_16x16x32_f16(al[m], bh[n], acc[m][n], 0, 0, 0);
    __syncthreads();
    cur ^= 1;
  }

  const int fq = lane >> 4;
  float bz[4];
#pragma unroll
  for (int n = 0; n < 4; ++n) bz[n] = bias[n0 + wc * 64 + n * 16 + fr];

  if (EPI == 0) {
    f16* Ohi = (f16*)Ov;
    f16* Olo = Ohi + (size_t)M * N;
#pragma unroll
    for (int m = 0; m < 4; ++m)
#pragma unroll
      for (int n = 0; n < 4; ++n) {
        const int col = n0 + wc * 64 + n * 16 + fr;
#pragma unroll
        for (int r = 0; r < 4; ++r) {
          const int row = m0 + wr * 64 + m * 16 + fq * 4 + r;
          float v = fmaxf(acc[m][n][r] + bz[n], 0.f);
          f16 h = (f16)v;
          f16 l = (f16)(v - (float)h);
          Ohi[(size_t)row * N + col] = h;
          Olo[(size_t)row * N + col] = l;
        }
      }
  } else {
    float* O = (float*)Ov;
#pragma unroll
    for (int m = 0; m < 4; ++m)
#pragma unroll
      for (int n = 0; n < 4; ++n) {
        const int col = n0 + wc * 64 + n * 16 + fr;
#pragma unroll
        for (int r = 0; r < 4; ++r) {
          const int row = m0 + wr * 64 + m * 16 + fq * 4 + r;
          const int grow = roff + row;
          const int bb = grow >> 11, ss = grow & 2047;
          O[(((size_t)(bb * 64 + (col >> 3)) * 2048 + ss) << 3) + (col & 7)] = acc[m][n][r] + bz[n];
        }
      }
  }
}

// ---------------------------------------------------------------------------
// Chunked affine scan (3 phases), per mega-chunk of 2 batches (128 streams).
// ---------------------------------------------------------------------------
#define SCH2 16
#define SEGL 128
#define NSEG 16

__global__ __launch_bounds__(256)
void scan_part1(const float* __restrict__ BLKTc, const float* __restrict__ VTc,
                float* __restrict__ Msum, float* __restrict__ Csum) {
  __shared__ __align__(16) float Abuf[4][2][SCH2 * 64];
  __shared__ __align__(16) float vbuf[4][2][SCH2 * 8];
  const int w = threadIdx.x >> 6, lane = threadIdx.x & 63;
  const int id = blockIdx.x * 4 + w;       // stream_local*NSEG + t, 0..2047
  const int stream = id >> 4, t = id & 15;
  const int i = lane >> 3, j = lane & 7;
  const float* Ab = BLKTc + (size_t)stream * (2048 * 64) + (size_t)t * (SEGL * 64);
  const float* Vb = VTc + (size_t)stream * (2048 * 8) + (size_t)t * (SEGL * 8);

  float m = (i == j) ? 1.f : 0.f;
  float cj = 0.f;

  float4 ra[4]; float2 rv;
  auto loadc = [&](int c) {
    const float* sA = Ab + c * (SCH2 * 64);
#pragma unroll
    for (int q = 0; q < 4; ++q) ra[q] = *(const float4*)(sA + q * 256 + lane * 4);
    rv = *(const float2*)(Vb + c * (SCH2 * 8) + lane * 2);
  };
  auto store_lds = [&](int slot) {
#pragma unroll
    for (int q = 0; q < 4; ++q)
      *(float4*)&Abuf[w][slot][q * 256 + lane * 4] = ra[q];
    *(float2*)&vbuf[w][slot][lane * 2] = rv;
  };

  loadc(0); store_lds(0);
  int cur = 0;
  const int NC = SEGL / SCH2;
  for (int c = 0; c < NC; ++c) {
    if (c + 1 < NC) loadc(c + 1);
#pragma unroll
    for (int s = 0; s < SCH2; ++s) {
      const float aij = Abuf[w][cur][s * 64 + lane];
      float p = aij * cj;
      p += __shfl_xor(p, 1);
      p += __shfl_xor(p, 2);
      p += __shfl_xor(p, 4);
      const float cn = p + vbuf[w][cur][s * 8 + i];
      cj = __shfl(cn, j << 3);
      float arow[8];
      *(float4*)&arow[0] = *(const float4*)&Abuf[w][cur][s * 64 + i * 8];
      *(float4*)&arow[4] = *(const float4*)&Abuf[w][cur][s * 64 + i * 8 + 4];
      float mn = 0.f;
#pragma unroll
      for (int k = 0; k < 8; ++k)
        mn = fmaf(arow[k], __shfl(m, (k << 3) | j), mn);
      m = mn;
    }
    if (c + 1 < NC) store_lds(cur ^ 1);
    cur ^= 1;
  }
  Msum[(size_t)id * 64 + lane] = m;
  if (lane < 8) Csum[(size_t)id * 8 + lane] = cj;
}

__global__ __launch_bounds__(64)
void scan_part2(const float* __restrict__ Msum, const float* __restrict__ Csum,
                const float* __restrict__ a0, float* __restrict__ Ybnd) {
  const int stream = blockIdx.x;  // local stream: b_local*64 + h
  const int lane = threadIdx.x;
  const int i = lane >> 3, j = lane & 7;
  const int h = stream & 63;
  float y = a0[h * 8 + j];
  for (int t = 0; t < NSEG; ++t) {
    const size_t sid = (size_t)stream * NSEG + t;
    if (lane < 8) Ybnd[sid * 8 + lane] = y;
    float p = Msum[sid * 64 + lane] * y;
    p += __shfl_xor(p, 1);
    p += __shfl_xor(p, 2);
    p += __shfl_xor(p, 4);
    const float yn = p + Csum[sid * 8 + i];
    y = __shfl(yn, j << 3);
  }
}

__global__ __launch_bounds__(256)
void scan_part3(const float* __restrict__ BLKTc, const float* __restrict__ VTc,
                const float* __restrict__ Ybnd, float* __restrict__ outc) {
  __shared__ __align__(16) float Abuf[4][2][SCH2 * 64];
  __shared__ __align__(16) float vbuf[4][2][SCH2 * 8];
  const int w = threadIdx.x >> 6, lane = threadIdx.x & 63;
  const int id = blockIdx.x * 4 + w;
  const int stream = id >> 4, t = id & 15;
  const int b = stream >> 6, h = stream & 63;  // local batch
  const int i = lane >> 3, j = lane & 7;
  const float* Ab = BLKTc + (size_t)stream * (2048 * 64) + (size_t)t * (SEGL * 64);
  const float* Vb = VTc + (size_t)stream * (2048 * 8) + (size_t)t * (SEGL * 8);
  float* ob = outc + (size_t)b * (2048 * 512) + (size_t)(t * SEGL) * 512 + h * 8;

  float y = Ybnd[(size_t)id * 8 + j];

  float4 ra[4]; float2 rv;
  auto loadc = [&](int c) {
    const float* sA = Ab + c * (SCH2 * 64);
#pragma unroll
    for (int q = 0; q < 4; ++q) ra[q] = *(const float4*)(sA + q * 256 + lane * 4);
    rv = *(const float2*)(Vb + c * (SCH2 * 8) + lane * 2);
  };
  auto store_lds = [&](int slot) {
#pragma unroll
    for (int q = 0; q < 4; ++q)
      *(float4*)&Abuf[w][slot][q * 256 + lane * 4] = ra[q];
    *(float2*)&vbuf[w][slot][lane * 2] = rv;
  };

  loadc(0); store_lds(0);
  int cur = 0;
  const int NC = SEGL / SCH2;
  for (int c = 0; c < NC; ++c) {
    if (c + 1 < NC) loadc(c + 1);
#pragma unroll
    for (int s = 0; s < SCH2; ++s) {
      const float aij = Abuf[w][cur][s * 64 + lane];
      float p = aij * y;
      p += __shfl_xor(p, 1);
      p += __shfl_xor(p, 2);
      p += __shfl_xor(p, 4);
      const float yn = p + vbuf[w][cur][s * 8 + i];
      if (j == 0) ob[(size_t)(c * SCH2 + s) * 512 + i] = yn;
      y = __shfl(yn, j << 3);
    }
    if (c + 1 < NC) store_lds(cur ^ 1);
    cur ^= 1;
  }
}

// ---------------------------------------------------------------------------
extern "C" void kernel_launch(void* const* d_in, const int* in_sizes, int n_in,
                              void* d_out, int out_size, void* d_ws, size_t ws_size,
                              hipStream_t stream) {
  const float* x  = (const float*)d_in[0];
  const float* W1 = (const float*)d_in[1];
  const float* b1 = (const float*)d_in[2];
  const float* W2 = (const float*)d_in[3];
  const float* b2 = (const float*)d_in[4];
  const float* V1 = (const float*)d_in[5];
  const float* c1 = (const float*)d_in[6];
  const float* V2 = (const float*)d_in[7];
  const float* c2 = (const float*)d_in[8];
  const float* a0 = (const float*)d_in[9];
  float* out = (float*)d_out;

  dim3 blk(256);

  // Workspace layout (bytes), total ~246 MB (< proven 267.6 MB).
  char* base = (char*)d_ws;
  f16* W2hi   = (f16*)base;                        //  33554432 B
  f16* W2lo   = (f16*)(base + 33554432ull);        //  33554432 B
  f16* H1hi   = (f16*)(base + 67108864ull);        //  67108864 B (hi+lo, M=4096)
  float* BLKTc= (float*)(base + 134217728ull);     //  67108864 B [2][64][2048][64]
  float* VT   = (float*)(base + 201326592ull);     //  16777216 B [4][64][2048][8]
  f16* xfhi   = (f16*)(base + 218103808ull);       //   8388608 B (full x hi)
  f16* xflo   = (f16*)(base + 226492416ull);       //   8388608 B
  f16* W1hi   = (f16*)(base + 234881024ull);       //   4194304 B
  f16* W1lo   = (f16*)(base + 239075328ull);
  f16* V1hi   = (f16*)(base + 243269632ull);       //    524288 B
  f16* V1lo   = (f16*)(base + 243793920ull);
  f16* V2hi   = (f16*)(base + 244318208ull);
  f16* V2lo   = (f16*)(base + 244842496ull);
  float* Msum = (float*)(base + 245366784ull);     //    524288 B (2048*64)
  float* Csum = (float*)(base + 245891072ull);     //     65536 B
  float* Ybnd = (float*)(base + 245956608ull);     //     65536 B
  f16* HVhi   = H1hi;  // transient alias: HV planes (16.8 MB) before chunk loop

  // ---- splits ----
  split_kernel<<<4096, blk, 0, stream>>>(x, xfhi, xflo, 4194304);
  split_kernel<<<2048, blk, 0, stream>>>(W1, W1hi, W1lo, 2097152);
  split_kernel<<<16384, blk, 0, stream>>>(W2, W2hi, W2lo, 16777216);
  split_kernel<<<256, blk, 0, stream>>>(V1, V1hi, V1lo, 262144);
  split_kernel<<<256, blk, 0, stream>>>(V2, V2hi, V2lo, 262144);

  // ---- V path (full M, before H1c overwrites HV region) ----
  gemm_dma2<0><<<256, blk, 0, stream>>>(
      xfhi, xflo, V1hi, V1lo, c1, HVhi, 8192, 512, 512, 0, 6);
  gemm_dma2<2><<<256, blk, 0, stream>>>(
      HVhi, HVhi + (size_t)8192 * 512, V2hi, V2lo, c2, VT, 8192, 512, 512, 0, 6);

  // ---- MLP + scan in 2 mega-chunks of 2 batches (M=4096) ----
  for (int c = 0; c < 2; ++c) {
    const f16* xahi = xfhi + (size_t)c * 4096 * 512;
    const f16* xalo = xflo + (size_t)c * 4096 * 512;
    // H1 = relu(xc @ W1^T + b1) -> hi/lo planes     M=4096 N=4096 K=512
    gemm_sb<0><<<1024, blk, 0, stream>>>(
        xahi, xalo, W1hi, W1lo, b1, H1hi, 4096, 4096, 512, 0, 5);
    // BLKTc (norm-fused) = H1 @ W2^T + b2           M=4096 N=4096 K=4096
    gemm_sb<1><<<1024, blk, 0, stream>>>(
        H1hi, H1hi + (size_t)4096 * 4096, W2hi, W2lo, b2, BLKTc,
        4096, 4096, 4096, 0, 5);
    // per-chunk scan (128 streams)
    const float* VTc = VT + (size_t)c * 2 * 64 * 2048 * 8;
    float* outc = out + (size_t)c * 2 * 2048 * 512;
    scan_part1<<<512, blk, 0, stream>>>(BLKTc, VTc, Msum, Csum);
    scan_part2<<<128, 64, 0, stream>>>(Msum, Csum, a0, Ybnd);
    scan_part3<<<512, blk, 0, stream>>>(BLKTc, VTc, Ybnd, outc);
  }
}

// Round 22
// 943.702 us; speedup vs baseline: 1.4424x; 1.4424x over previous
//
#include <hip/hip_runtime.h>
#include <hip/hip_bf16.h>
#include <cstddef>

// Problem constants: BS=4, SEQ=2048, EMB=512, BD=8, H=64; tokens M=8192.

typedef _Float16 f16;
typedef _Float16 f16x4 __attribute__((ext_vector_type(4)));
typedef _Float16 f16x8 __attribute__((ext_vector_type(8)));
typedef float f32x4 __attribute__((ext_vector_type(4)));

// ---------------------------------------------------------------------------
// One-shot fp32 -> (hi,lo) f16 plane split.  v = hi + lo.
// ---------------------------------------------------------------------------
__global__ __launch_bounds__(256)
void split_kernel(const float* __restrict__ in, f16* __restrict__ hi,
                  f16* __restrict__ lo, int n) {
  const int idx = (blockIdx.x * 256 + threadIdx.x) * 4;
  if (idx >= n) return;
  float4 v = *(const float4*)(in + idx);
  f16x4 h, l;
  h.x = (f16)v.x; l.x = (f16)(v.x - (float)h.x);
  h.y = (f16)v.y; l.y = (f16)(v.y - (float)h.y);
  h.z = (f16)v.z; l.z = (f16)(v.z - (float)h.z);
  h.w = (f16)v.w; l.w = (f16)(v.w - (float)h.w);
  *(f16x4*)(hi + idx) = h;
  *(f16x4*)(lo + idx) = l;
}

// ---------------------------------------------------------------------------
// 256x256-tile DMA-staged split-f16 GEMM (SESSION-BEST config, R15/R20):
// 8 waves (2M x 4N), wave tile 128x64, BK=32, double-buffered 128KB LDS,
// loop: stage(next) -> 24 ds_reads -> 3 passes of 32 independent MFMAs
// (hh, hl, lh; per-acc order preserved -> bit-identical) -> __syncthreads.
// Measured 943.7us total, gemm<1> 352us @ MfmaUtil 54% (reproduced twice).
// Ledger: 4 in-block schedule variants null/neg; 32x32 shape -17%; 1-buf
// 256^2 impossible (grid==CUs); 1-buf 128^2 4blk fetch-bound (-47%);
// (512,4) spill trap.  Terminal configuration.
// Rotate swizzle (4 slots/16B per row) on global src + ds_read; LDS linear.
// EPI 0: relu -> hi/lo plane out; EPI 1: fused block-norm -> BLKT [b,h,s,64].
// ---------------------------------------------------------------------------
template<int EPI>
__global__ __launch_bounds__(512, 2)
void gemm_big(const f16* __restrict__ Ahi, const f16* __restrict__ Alo,
              const f16* __restrict__ Bhi, const f16* __restrict__ Blo,
              const float* __restrict__ bias, void* __restrict__ Ov,
              int M, int N, int K, int roff) {
  __shared__ f16 S[2][4][256 * 32];
  const int tid = threadIdx.x, lane = tid & 63, wid = tid >> 6;
  const int m0 = blockIdx.y << 8, n0 = blockIdx.x << 8;
  const int wr = wid >> 2, wc = wid & 3;            // wave tile: rows wr*128, cols wc*64
  const int fr = lane & 15, g = lane >> 4;          // frag row sel / 16B chunk
  const int r_sub = lane >> 2, lc = lane & 3;       // staging row / stored slot
  const int p = wid >> 1, half = wid & 1;           // staged plane / half

  f32x4 acc[8][4];
#pragma unroll
  for (int m = 0; m < 8; ++m)
#pragma unroll
    for (int n = 0; n < 4; ++n) acc[m][n] = (f32x4)0.f;

  const f16* gsrc = (p == 0) ? Ahi + (size_t)m0 * K
                  : (p == 1) ? Alo + (size_t)m0 * K
                  : (p == 2) ? Bhi + (size_t)n0 * K
                             : Blo + (size_t)n0 * K;

  auto stage = [&](int b, int k0) {                 // 8 gload_lds per wave
    f16* ld = &S[b][p][half * 4096];
#pragma unroll
    for (int i = 0; i < 8; ++i) {
      const int r = half * 128 + i * 16 + r_sub;    // plane row 0..255
      const int sg = (lc - r - (r >> 2)) & 3;       // source chunk for slot lc
      const f16* sp = gsrc + (size_t)r * K + k0 + sg * 8;
      __builtin_amdgcn_global_load_lds(
          (const __attribute__((address_space(1))) unsigned int*)sp,
          (__attribute__((address_space(3))) unsigned int*)(ld + i * 512),
          16, 0, 0);
    }
  };

  const int NT = K >> 5;
  stage(0, 0);
  __syncthreads();
  int cur = 0;
  for (int t = 0; t < NT; ++t) {
    if (t + 1 < NT) stage(cur ^ 1, (t + 1) << 5);   // loads fly under compute

    f16x8 ah[8], al[8], bh[4], bl[4];
#pragma unroll
    for (int m = 0; m < 8; ++m) {
      const int rr = wr * 128 + m * 16 + fr;
      const int off = rr * 32 + (((g + rr + (rr >> 2)) & 3) << 3);
      ah[m] = *(const f16x8*)&S[cur][0][off];
      al[m] = *(const f16x8*)&S[cur][1][off];
    }
#pragma unroll
    for (int n = 0; n < 4; ++n) {
      const int rr = wc * 64 + n * 16 + fr;
      const int off = rr * 32 + (((g + rr + (rr >> 2)) & 3) << 3);
      bh[n] = *(const f16x8*)&S[cur][2][off];
      bl[n] = *(const f16x8*)&S[cur][3][off];
    }
    // Pass 1: all hi*hi (32 independent MFMAs)
#pragma unroll
    for (int m = 0; m < 8; ++m)
#pragma unroll
      for (int n = 0; n < 4; ++n)
        acc[m][n] = __builtin_amdgcn_mfma_f32_16x16x32_f16(ah[m], bh[n], acc[m][n], 0, 0, 0);
    // Pass 2: all hi*lo
#pragma unroll
    for (int m = 0; m < 8; ++m)
#pragma unroll
      for (int n = 0; n < 4; ++n)
        acc[m][n] = __builtin_amdgcn_mfma_f32_16x16x32_f16(ah[m], bl[n], acc[m][n], 0, 0, 0);
    // Pass 3: all lo*hi
#pragma unroll
    for (int m = 0; m < 8; ++m)
#pragma unroll
      for (int n = 0; n < 4; ++n)
        acc[m][n] = __builtin_amdgcn_mfma_f32_16x16x32_f16(al[m], bh[n], acc[m][n], 0, 0, 0);

    __syncthreads();  // drain staged loads (after compute) + buffer WAR sync
    cur ^= 1;
  }

  // Epilogue.  frag (m,n): col = n0+wc*64+n*16+fr, row = m0+wr*128+m*16+fq*4+r
  const int fq = lane >> 4;
  float bz[4];
#pragma unroll
  for (int n = 0; n < 4; ++n) bz[n] = bias[n0 + wc * 64 + n * 16 + fr];

  if (EPI == 0) {
    f16* Ohi = (f16*)Ov;
    f16* Olo = Ohi + (size_t)M * N;
#pragma unroll
    for (int m = 0; m < 8; ++m)
#pragma unroll
      for (int n = 0; n < 4; ++n) {
        const int col = n0 + wc * 64 + n * 16 + fr;
#pragma unroll
        for (int r = 0; r < 4; ++r) {
          const int row = m0 + wr * 128 + m * 16 + fq * 4 + r;
          float v = fmaxf(acc[m][n][r] + bz[n], 0.f);
          f16 h = (f16)v;
          f16 l = (f16)(v - (float)h);
          Ohi[(size_t)row * N + col] = h;
          Olo[(size_t)row * N + col] = l;
        }
      }
  } else {
    // fused block-norm: wave col span = one head (64 cols); i=2n+(fr>>3), j=fr&7
    float* O = (float*)Ov;
#pragma unroll
    for (int m = 0; m < 8; ++m) {
#pragma unroll
      for (int r = 0; r < 4; ++r) {
        float v[4];
#pragma unroll
        for (int n = 0; n < 4; ++n) v[n] = acc[m][n][r] + bz[n];
        float s = v[0] + v[1] + v[2] + v[3];
        s += __shfl_xor(s, 8);
        const float mean = s * 0.125f;
        float t = 0.f;
#pragma unroll
        for (int n = 0; n < 4; ++n) {
          v[n] -= mean;
          t += exp2f(1.2f * log2f(fabsf(v[n])));  // |x|^1.2 (0 -> 0)
        }
        t += __shfl_xor(t, 8);                    // sum over i
        float nrm = exp2f((1.0f / 1.2f) * log2f(t));
        nrm = fmaxf(nrm, __shfl_xor(nrm, 1));
        nrm = fmaxf(nrm, __shfl_xor(nrm, 2));
        nrm = fmaxf(nrm, __shfl_xor(nrm, 4));     // max over j
        const float inv = 1.f / nrm;
        const int row = m0 + wr * 128 + m * 16 + fq * 4 + r;
        const int grow = roff + row;
        const int bb = grow >> 11, ss = grow & 2047;  // local batch (M=4096)
#pragma unroll
        for (int n = 0; n < 4; ++n) {
          const int col = n0 + wc * 64 + n * 16 + fr;
          O[(((size_t)(bb * 64 + (col >> 6)) * 2048 + ss) << 6) + (col & 63)] = v[n] * inv;
        }
      }
    }
  }
}

// ---------------------------------------------------------------------------
// 128x128 DMA-staged GEMM (V-path only); proven 16x16 path, 3-pass order.
// EPI 0: relu -> hi/lo planes; EPI 2: plain -> VT [b,h,s,8].
// ---------------------------------------------------------------------------
template<int EPI>
__global__ __launch_bounds__(256, 2)
void gemm_dma2(const f16* __restrict__ Ahi, const f16* __restrict__ Alo,
               const f16* __restrict__ Bhi, const f16* __restrict__ Blo,
               const float* __restrict__ bias, void* __restrict__ Ov,
               int M, int N, int K, int roff, int lg_mb) {
  __shared__ f16 S[2][4][128 * 32];
  const int tid = threadIdx.x, lane = tid & 63, wid = tid >> 6;
  const int total = gridDim.x, chunk = total >> 3;
  const int swz = (blockIdx.x & 7) * chunk + (blockIdx.x >> 3);
  const int mtile = swz & ((1 << lg_mb) - 1);
  const int ntile = swz >> lg_mb;
  const int m0 = mtile << 7, n0 = ntile << 7;
  const int wr = wid >> 1, wc = wid & 1;
  const int fr = lane & 15, g = lane >> 4;
  const int r_sub = lane >> 2, lc = lane & 3;

  f32x4 acc[4][4];
#pragma unroll
  for (int m = 0; m < 4; ++m)
#pragma unroll
    for (int n = 0; n < 4; ++n) acc[m][n] = (f32x4)0.f;

  const f16* gsrc = (wid == 0) ? Ahi + (size_t)m0 * K
                  : (wid == 1) ? Alo + (size_t)m0 * K
                  : (wid == 2) ? Bhi + (size_t)n0 * K
                               : Blo + (size_t)n0 * K;

  auto stage = [&](int b, int k0) {
    f16* ld = &S[b][wid][0];
#pragma unroll
    for (int i = 0; i < 8; ++i) {
      const int r = i * 16 + r_sub;
      const int sg = (lc - r - (r >> 2)) & 3;
      const f16* sp = gsrc + (size_t)r * K + k0 + sg * 8;
      __builtin_amdgcn_global_load_lds(
          (const __attribute__((address_space(1))) unsigned int*)sp,
          (__attribute__((address_space(3))) unsigned int*)(ld + i * 512),
          16, 0, 0);
    }
  };

  const int NT = K >> 5;
  stage(0, 0);
  __syncthreads();
  int cur = 0;
  for (int t = 0; t < NT; ++t) {
    if (t + 1 < NT) stage(cur ^ 1, (t + 1) << 5);
    f16x8 ah[4], al[4], bh[4], bl[4];
#pragma unroll
    for (int m = 0; m < 4; ++m) {
      const int rr = wr * 64 + m * 16 + fr;
      const int off = rr * 32 + (((g + rr + (rr >> 2)) & 3) << 3);
      ah[m] = *(const f16x8*)&S[cur][0][off];
      al[m] = *(const f16x8*)&S[cur][1][off];
    }
#pragma unroll
    for (int n = 0; n < 4; ++n) {
      const int rr = wc * 64 + n * 16 + fr;
      const int off = rr * 32 + (((g + rr + (rr >> 2)) & 3) << 3);
      bh[n] = *(const f16x8*)&S[cur][2][off];
      bl[n] = *(const f16x8*)&S[cur][3][off];
    }
#pragma unroll
    for (int m = 0; m < 4; ++m)
#pragma unroll
      for (int n = 0; n < 4; ++n)
        acc[m][n] = __builtin_amdgcn_mfma_f32_16x16x32_f16(ah[m], bh[n], acc[m][n], 0, 0, 0);
#pragma unroll
    for (int m = 0; m < 4; ++m)
#pragma unroll
      for (int n = 0; n < 4; ++n)
        acc[m][n] = __builtin_amdgcn_mfma_f32_16x16x32_f16(ah[m], bl[n], acc[m][n], 0, 0, 0);
#pragma unroll
    for (int m = 0; m < 4; ++m)
#pragma unroll
      for (int n = 0; n < 4; ++n)
        acc[m][n] = __builtin_amdgcn_mfma_f32_16x16x32_f16(al[m], bh[n], acc[m][n], 0, 0, 0);
    __syncthreads();
    cur ^= 1;
  }

  const int fq = lane >> 4;
  float bz[4];
#pragma unroll
  for (int n = 0; n < 4; ++n) bz[n] = bias[n0 + wc * 64 + n * 16 + fr];

  if (EPI == 0) {
    f16* Ohi = (f16*)Ov;
    f16* Olo = Ohi + (size_t)M * N;
#pragma unroll
    for (int m = 0; m < 4; ++m)
#pragma unroll
      for (int n = 0; n < 4; ++n) {
        const int col = n0 + wc * 64 + n * 16 + fr;
#pragma unroll
        for (int r = 0; r < 4; ++r) {
          const int row = m0 + wr * 64 + m * 16 + fq * 4 + r;
          float v = fmaxf(acc[m][n][r] + bz[n], 0.f);
          f16 h = (f16)v;
          f16 l = (f16)(v - (float)h);
          Ohi[(size_t)row * N + col] = h;
          Olo[(size_t)row * N + col] = l;
        }
      }
  } else {
    float* O = (float*)Ov;
#pragma unroll
    for (int m = 0; m < 4; ++m)
#pragma unroll
      for (int n = 0; n < 4; ++n) {
        const int col = n0 + wc * 64 + n * 16 + fr;
#pragma unroll
        for (int r = 0; r < 4; ++r) {
          const int row = m0 + wr * 64 + m * 16 + fq * 4 + r;
          const int grow = roff + row;
          const int bb = grow >> 11, ss = grow & 2047;
          O[(((size_t)(bb * 64 + (col >> 3)) * 2048 + ss) << 3) + (col & 7)] = acc[m][n][r] + bz[n];
        }
      }
  }
}

// ---------------------------------------------------------------------------
// Chunked affine scan (3 phases), per mega-chunk of 2 batches (128 streams).
// ---------------------------------------------------------------------------
#define SCH2 16
#define SEGL 128
#define NSEG 16

__global__ __launch_bounds__(256)
void scan_part1(const float* __restrict__ BLKTc, const float* __restrict__ VTc,
                float* __restrict__ Msum, float* __restrict__ Csum) {
  __shared__ __align__(16) float Abuf[4][2][SCH2 * 64];
  __shared__ __align__(16) float vbuf[4][2][SCH2 * 8];
  const int w = threadIdx.x >> 6, lane = threadIdx.x & 63;
  const int id = blockIdx.x * 4 + w;       // stream_local*NSEG + t, 0..2047
  const int stream = id >> 4, t = id & 15;
  const int i = lane >> 3, j = lane & 7;
  const float* Ab = BLKTc + (size_t)stream * (2048 * 64) + (size_t)t * (SEGL * 64);
  const float* Vb = VTc + (size_t)stream * (2048 * 8) + (size_t)t * (SEGL * 8);

  float m = (i == j) ? 1.f : 0.f;
  float cj = 0.f;

  float4 ra[4]; float2 rv;
  auto loadc = [&](int c) {
    const float* sA = Ab + c * (SCH2 * 64);
#pragma unroll
    for (int q = 0; q < 4; ++q) ra[q] = *(const float4*)(sA + q * 256 + lane * 4);
    rv = *(const float2*)(Vb + c * (SCH2 * 8) + lane * 2);
  };
  auto store_lds = [&](int slot) {
#pragma unroll
    for (int q = 0; q < 4; ++q)
      *(float4*)&Abuf[w][slot][q * 256 + lane * 4] = ra[q];
    *(float2*)&vbuf[w][slot][lane * 2] = rv;
  };

  loadc(0); store_lds(0);
  int cur = 0;
  const int NC = SEGL / SCH2;
  for (int c = 0; c < NC; ++c) {
    if (c + 1 < NC) loadc(c + 1);
#pragma unroll
    for (int s = 0; s < SCH2; ++s) {
      const float aij = Abuf[w][cur][s * 64 + lane];
      float p = aij * cj;
      p += __shfl_xor(p, 1);
      p += __shfl_xor(p, 2);
      p += __shfl_xor(p, 4);
      const float cn = p + vbuf[w][cur][s * 8 + i];
      cj = __shfl(cn, j << 3);
      float arow[8];
      *(float4*)&arow[0] = *(const float4*)&Abuf[w][cur][s * 64 + i * 8];
      *(float4*)&arow[4] = *(const float4*)&Abuf[w][cur][s * 64 + i * 8 + 4];
      float mn = 0.f;
#pragma unroll
      for (int k = 0; k < 8; ++k)
        mn = fmaf(arow[k], __shfl(m, (k << 3) | j), mn);
      m = mn;
    }
    if (c + 1 < NC) store_lds(cur ^ 1);
    cur ^= 1;
  }
  Msum[(size_t)id * 64 + lane] = m;
  if (lane < 8) Csum[(size_t)id * 8 + lane] = cj;
}

__global__ __launch_bounds__(64)
void scan_part2(const float* __restrict__ Msum, const float* __restrict__ Csum,
                const float* __restrict__ a0, float* __restrict__ Ybnd) {
  const int stream = blockIdx.x;  // local stream: b_local*64 + h
  const int lane = threadIdx.x;
  const int i = lane >> 3, j = lane & 7;
  const int h = stream & 63;
  float y = a0[h * 8 + j];
  for (int t = 0; t < NSEG; ++t) {
    const size_t sid = (size_t)stream * NSEG + t;
    if (lane < 8) Ybnd[sid * 8 + lane] = y;
    float p = Msum[sid * 64 + lane] * y;
    p += __shfl_xor(p, 1);
    p += __shfl_xor(p, 2);
    p += __shfl_xor(p, 4);
    const float yn = p + Csum[sid * 8 + i];
    y = __shfl(yn, j << 3);
  }
}

__global__ __launch_bounds__(256)
void scan_part3(const float* __restrict__ BLKTc, const float* __restrict__ VTc,
                const float* __restrict__ Ybnd, float* __restrict__ outc) {
  __shared__ __align__(16) float Abuf[4][2][SCH2 * 64];
  __shared__ __align__(16) float vbuf[4][2][SCH2 * 8];
  const int w = threadIdx.x >> 6, lane = threadIdx.x & 63;
  const int id = blockIdx.x * 4 + w;
  const int stream = id >> 4, t = id & 15;
  const int b = stream >> 6, h = stream & 63;  // local batch
  const int i = lane >> 3, j = lane & 7;
  const float* Ab = BLKTc + (size_t)stream * (2048 * 64) + (size_t)t * (SEGL * 64);
  const float* Vb = VTc + (size_t)stream * (2048 * 8) + (size_t)t * (SEGL * 8);
  float* ob = outc + (size_t)b * (2048 * 512) + (size_t)(t * SEGL) * 512 + h * 8;

  float y = Ybnd[(size_t)id * 8 + j];

  float4 ra[4]; float2 rv;
  auto loadc = [&](int c) {
    const float* sA = Ab + c * (SCH2 * 64);
#pragma unroll
    for (int q = 0; q < 4; ++q) ra[q] = *(const float4*)(sA + q * 256 + lane * 4);
    rv = *(const float2*)(Vb + c * (SCH2 * 8) + lane * 2);
  };
  auto store_lds = [&](int slot) {
#pragma unroll
    for (int q = 0; q < 4; ++q)
      *(float4*)&Abuf[w][slot][q * 256 + lane * 4] = ra[q];
    *(float2*)&vbuf[w][slot][lane * 2] = rv;
  };

  loadc(0); store_lds(0);
  int cur = 0;
  const int NC = SEGL / SCH2;
  for (int c = 0; c < NC; ++c) {
    if (c + 1 < NC) loadc(c + 1);
#pragma unroll
    for (int s = 0; s < SCH2; ++s) {
      const float aij = Abuf[w][cur][s * 64 + lane];
      float p = aij * y;
      p += __shfl_xor(p, 1);
      p += __shfl_xor(p, 2);
      p += __shfl_xor(p, 4);
      const float yn = p + vbuf[w][cur][s * 8 + i];
      if (j == 0) ob[(size_t)(c * SCH2 + s) * 512 + i] = yn;
      y = __shfl(yn, j << 3);
    }
    if (c + 1 < NC) store_lds(cur ^ 1);
    cur ^= 1;
  }
}

// ---------------------------------------------------------------------------
extern "C" void kernel_launch(void* const* d_in, const int* in_sizes, int n_in,
                              void* d_out, int out_size, void* d_ws, size_t ws_size,
                              hipStream_t stream) {
  const float* x  = (const float*)d_in[0];
  const float* W1 = (const float*)d_in[1];
  const float* b1 = (const float*)d_in[2];
  const float* W2 = (const float*)d_in[3];
  const float* b2 = (const float*)d_in[4];
  const float* V1 = (const float*)d_in[5];
  const float* c1 = (const float*)d_in[6];
  const float* V2 = (const float*)d_in[7];
  const float* c2 = (const float*)d_in[8];
  const float* a0 = (const float*)d_in[9];
  float* out = (float*)d_out;

  dim3 blk(256);

  // Workspace layout (bytes), total ~246 MB (< proven 267.6 MB).
  char* base = (char*)d_ws;
  f16* W2hi   = (f16*)base;                        //  33554432 B
  f16* W2lo   = (f16*)(base + 33554432ull);        //  33554432 B
  f16* H1hi   = (f16*)(base + 67108864ull);        //  67108864 B (hi+lo, M=4096)
  float* BLKTc= (float*)(base + 134217728ull);     //  67108864 B [2][64][2048][64]
  float* VT   = (float*)(base + 201326592ull);     //  16777216 B [4][64][2048][8]
  f16* xfhi   = (f16*)(base + 218103808ull);       //   8388608 B (full x hi)
  f16* xflo   = (f16*)(base + 226492416ull);       //   8388608 B
  f16* W1hi   = (f16*)(base + 234881024ull);       //   4194304 B
  f16* W1lo   = (f16*)(base + 239075328ull);
  f16* V1hi   = (f16*)(base + 243269632ull);       //    524288 B
  f16* V1lo   = (f16*)(base + 243793920ull);
  f16* V2hi   = (f16*)(base + 244318208ull);
  f16* V2lo   = (f16*)(base + 244842496ull);
  float* Msum = (float*)(base + 245366784ull);     //    524288 B (2048*64)
  float* Csum = (float*)(base + 245891072ull);     //     65536 B
  float* Ybnd = (float*)(base + 245956608ull);     //     65536 B
  f16* HVhi   = H1hi;  // transient alias: HV planes (16.8 MB) before chunk loop

  // ---- splits ----
  split_kernel<<<4096, blk, 0, stream>>>(x, xfhi, xflo, 4194304);
  split_kernel<<<2048, blk, 0, stream>>>(W1, W1hi, W1lo, 2097152);
  split_kernel<<<16384, blk, 0, stream>>>(W2, W2hi, W2lo, 16777216);
  split_kernel<<<256, blk, 0, stream>>>(V1, V1hi, V1lo, 262144);
  split_kernel<<<256, blk, 0, stream>>>(V2, V2hi, V2lo, 262144);

  // ---- V path (full M, before H1c overwrites HV region) ----
  gemm_dma2<0><<<256, blk, 0, stream>>>(
      xfhi, xflo, V1hi, V1lo, c1, HVhi, 8192, 512, 512, 0, 6);
  gemm_dma2<2><<<256, blk, 0, stream>>>(
      HVhi, HVhi + (size_t)8192 * 512, V2hi, V2lo, c2, VT, 8192, 512, 512, 0, 6);

  // ---- MLP + scan in 2 mega-chunks of 2 batches (M=4096) ----
  for (int c = 0; c < 2; ++c) {
    const f16* xahi = xfhi + (size_t)c * 4096 * 512;
    const f16* xalo = xflo + (size_t)c * 4096 * 512;
    // H1 = relu(xc @ W1^T + b1) -> hi/lo planes     M=4096 N=4096 K=512
    gemm_big<0><<<dim3(16, 16), 512, 0, stream>>>(
        xahi, xalo, W1hi, W1lo, b1, H1hi, 4096, 4096, 512, 0);
    // BLKTc (norm-fused) = H1 @ W2^T + b2           M=4096 N=4096 K=4096
    gemm_big<1><<<dim3(16, 16), 512, 0, stream>>>(
        H1hi, H1hi + (size_t)4096 * 4096, W2hi, W2lo, b2, BLKTc,
        4096, 4096, 4096, 0);
    // per-chunk scan (128 streams)
    const float* VTc = VT + (size_t)c * 2 * 64 * 2048 * 8;
    float* outc = out + (size_t)c * 2 * 2048 * 512;
    scan_part1<<<512, blk, 0, stream>>>(BLKTc, VTc, Msum, Csum);
    scan_part2<<<128, 64, 0, stream>>>(Msum, Csum, a0, Ybnd);
    scan_part3<<<512, blk, 0, stream>>>(BLKTc, VTc, Ybnd, outc);
  }
}